// Round 1
// baseline (1015.304 us; speedup 1.0000x reference)
//
#include <hip/hip_runtime.h>
#include <hip/hip_bf16.h>

// GCN 3-layer forward on MI355X.
// N=100000 nodes, E=1.6M edges, F=64, HID1=HID2=128.
//
// Key identities used:
//   out = A_norm @ (x @ W^T) + b  ==  (A_norm @ x) @ W^T + b   (agg is linear)
//   -> aggregate at 64 feats for layers 1 and 3, 128 for layer 2.
//   A_norm row i:  agg[i] = dinv[i] * ( sum_{e->i} dinv[src_e]*h[src_e] + dinv[i]*h[i] )
// CSR built on-device each call (counts -> scan -> fill); pull-based agg, no atomics
// on feature data.

#define TPB 256

// ---------------- CSR build ----------------

__global__ void k_zero_i32(int* __restrict__ p, int n) {
  int i = blockIdx.x * blockDim.x + threadIdx.x;
  if (i < n) p[i] = 0;
}

__global__ void k_count(const int* __restrict__ dst, int E, int* __restrict__ counts) {
  int e = blockIdx.x * blockDim.x + threadIdx.x;
  if (e < E) atomicAdd(&counts[dst[e]], 1);
}

__global__ __launch_bounds__(1024) void k_scan(const int* __restrict__ counts, int N, int E,
                                               int* __restrict__ rowptr, int* __restrict__ cursor,
                                               float* __restrict__ dinv) {
  __shared__ int sums[1024];
  int t = threadIdx.x;
  int chunk = (N + 1023) >> 10;
  int beg = t * chunk;
  int end = min(beg + chunk, N);
  int s = 0;
  for (int i = beg; i < end; ++i) s += counts[i];
  sums[t] = s;
  __syncthreads();
  for (int off = 1; off < 1024; off <<= 1) {
    int v = (t >= off) ? sums[t - off] : 0;
    __syncthreads();
    sums[t] += v;
    __syncthreads();
  }
  int run = sums[t] - s;  // exclusive prefix
  for (int i = beg; i < end; ++i) {
    rowptr[i] = run;
    cursor[i] = run;
    dinv[i] = rsqrtf((float)(counts[i] + 1));  // +1 = self-loop
    run += counts[i];
  }
  if (t == 0) rowptr[N] = E;
}

__global__ void k_fill(const int* __restrict__ src, const int* __restrict__ dst, int E,
                       int* __restrict__ cursor, int* __restrict__ col) {
  int e = blockIdx.x * blockDim.x + threadIdx.x;
  if (e < E) {
    int d = dst[e];
    int pos = atomicAdd(&cursor[d], 1);
    col[pos] = src[e];
  }
}

// ---------------- aggregation (pull, wave per row) ----------------

// F=64: lane = feature. EPI: 0 = plain, 1 = +bias then row-softmax.
template <int EPI>
__global__ void k_agg64(const float* __restrict__ h, const float* __restrict__ dinv,
                        const int* __restrict__ rowptr, const int* __restrict__ col,
                        const float* __restrict__ bias, float* __restrict__ out, int N) {
  int wid = blockIdx.x * (TPB / 64) + (threadIdx.x >> 6);
  int lane = threadIdx.x & 63;
  if (wid >= N) return;
  float di = dinv[wid];
  float acc = di * h[(size_t)wid * 64 + lane];  // self-loop term (inside di* scale)
  int r0 = rowptr[wid], r1 = rowptr[wid + 1];
  for (int base = r0; base < r1; base += 64) {
    int m = min(64, r1 - base);
    int ce = (base + lane < r1) ? col[base + lane] : 0;
    for (int j = 0; j < m; ++j) {
      int s2 = __shfl(ce, j);
      acc += dinv[s2] * h[(size_t)s2 * 64 + lane];
    }
  }
  float v = di * acc;
  if (EPI == 1) {
    v += bias[lane];
    float mx = v;
    #pragma unroll
    for (int o = 32; o > 0; o >>= 1) mx = fmaxf(mx, __shfl_xor(mx, o));
    float p = expf(v - mx);
    float sum = p;
    #pragma unroll
    for (int o = 32; o > 0; o >>= 1) sum += __shfl_xor(sum, o);
    v = p / sum;
  }
  out[(size_t)wid * 64 + lane] = v;
}

// F=128: lane handles 2 consecutive feats (float2).
__global__ void k_agg128(const float* __restrict__ h, const float* __restrict__ dinv,
                         const int* __restrict__ rowptr, const int* __restrict__ col,
                         float* __restrict__ out, int N) {
  int wid = blockIdx.x * (TPB / 64) + (threadIdx.x >> 6);
  int lane = threadIdx.x & 63;
  if (wid >= N) return;
  float di = dinv[wid];
  const float2* h2 = (const float2*)h;
  float2 hv = h2[(size_t)wid * 64 + lane];
  float ax = di * hv.x, ay = di * hv.y;
  int r0 = rowptr[wid], r1 = rowptr[wid + 1];
  for (int base = r0; base < r1; base += 64) {
    int m = min(64, r1 - base);
    int ce = (base + lane < r1) ? col[base + lane] : 0;
    for (int j = 0; j < m; ++j) {
      int s2 = __shfl(ce, j);
      float ds = dinv[s2];
      float2 hh = h2[(size_t)s2 * 64 + lane];
      ax += ds * hh.x;
      ay += ds * hh.y;
    }
  }
  float2 o;
  o.x = di * ax;
  o.y = di * ay;
  ((float2*)out)[(size_t)wid * 64 + lane] = o;
}

// ---------------- dense GEMM: out[M][NOUT] = in[M][K] @ W[NOUT][K]^T (+bias)(relu) ----------------

template <int K, int NOUT, bool RELU, bool BIAS>
__global__ __launch_bounds__(256) void k_gemm(const float* __restrict__ in,
                                              const float* __restrict__ W,
                                              const float* __restrict__ bias,
                                              float* __restrict__ out, int M) {
  constexpr int KC = 64;           // K-chunk staged in LDS
  constexpr int R = 64;            // rows per block
  constexpr int TN = 4;            // cols per thread
  constexpr int NG = NOUT / TN;    // col groups (32 or 16)
  constexpr int RG = 256 / NG;     // row groups (8 or 16)
  constexpr int TM = R / RG;       // rows per thread (8 or 4)

  __shared__ float wT[KC][NOUT + 4];   // W^T chunk, padded
  __shared__ float inT[KC][R + 4];     // input^T chunk, padded

  int t = threadIdx.x;
  int ng = t % NG, rg = t / NG;
  int n0 = ng * TN, r0 = rg * TM;
  int rowbase = blockIdx.x * R;

  float acc[TM][TN];
  #pragma unroll
  for (int i = 0; i < TM; ++i)
    #pragma unroll
    for (int j = 0; j < TN; ++j) acc[i][j] = 0.0f;

  for (int kc = 0; kc < K; kc += KC) {
    // stage W chunk transposed: wT[k][n] = W[n][kc+k]
    constexpr int WF4 = NOUT * KC / 4;
    for (int m = t; m < WF4; m += 256) {
      int kk4 = m % (KC / 4);
      int n = m / (KC / 4);
      const float4 w4 = *(const float4*)&W[(size_t)n * K + kc + kk4 * 4];
      wT[kk4 * 4 + 0][n] = w4.x;
      wT[kk4 * 4 + 1][n] = w4.y;
      wT[kk4 * 4 + 2][n] = w4.z;
      wT[kk4 * 4 + 3][n] = w4.w;
    }
    // stage input chunk transposed: inT[k][r] = in[rowbase+r][kc+k]
    constexpr int IF4 = R * KC / 4;
    for (int m = t; m < IF4; m += 256) {
      int kk4 = m % (KC / 4);
      int r = m / (KC / 4);
      int row = rowbase + r;
      float4 v4 = make_float4(0.f, 0.f, 0.f, 0.f);
      if (row < M) v4 = *(const float4*)&in[(size_t)row * K + kc + kk4 * 4];
      inT[kk4 * 4 + 0][r] = v4.x;
      inT[kk4 * 4 + 1][r] = v4.y;
      inT[kk4 * 4 + 2][r] = v4.z;
      inT[kk4 * 4 + 3][r] = v4.w;
    }
    __syncthreads();

    #pragma unroll 8
    for (int k = 0; k < KC; ++k) {
      float4 w4 = *(const float4*)&wT[k][n0];
      float iv[TM];
      #pragma unroll
      for (int i = 0; i < TM; ++i) iv[i] = inT[k][r0 + i];
      #pragma unroll
      for (int i = 0; i < TM; ++i) {
        acc[i][0] += iv[i] * w4.x;
        acc[i][1] += iv[i] * w4.y;
        acc[i][2] += iv[i] * w4.z;
        acc[i][3] += iv[i] * w4.w;
      }
    }
    __syncthreads();
  }

  float4 b4 = make_float4(0.f, 0.f, 0.f, 0.f);
  if (BIAS) b4 = *(const float4*)&bias[n0];
  #pragma unroll
  for (int i = 0; i < TM; ++i) {
    int row = rowbase + r0 + i;
    if (row < M) {
      float4 o;
      o.x = acc[i][0] + b4.x;
      o.y = acc[i][1] + b4.y;
      o.z = acc[i][2] + b4.z;
      o.w = acc[i][3] + b4.w;
      if (RELU) {
        o.x = fmaxf(o.x, 0.f);
        o.y = fmaxf(o.y, 0.f);
        o.z = fmaxf(o.z, 0.f);
        o.w = fmaxf(o.w, 0.f);
      }
      *(float4*)&out[(size_t)row * NOUT + n0] = o;
    }
  }
}

// ---------------- launch ----------------

extern "C" void kernel_launch(void* const* d_in, const int* in_sizes, int n_in,
                              void* d_out, int out_size, void* d_ws, size_t ws_size,
                              hipStream_t stream) {
  const float* x  = (const float*)d_in[0];
  const int*   ei = (const int*)d_in[1];
  const float* W1 = (const float*)d_in[2];
  const float* b1 = (const float*)d_in[3];
  const float* W2 = (const float*)d_in[4];
  const float* b2 = (const float*)d_in[5];
  const float* W3 = (const float*)d_in[6];
  const float* b3 = (const float*)d_in[7];
  float* out = (float*)d_out;

  const int N = in_sizes[0] / 64;
  const int E = in_sizes[1] / 2;
  const int* esrc = ei;
  const int* edst = ei + E;

  // workspace carve (256B-aligned regions)
  char* w = (char*)d_ws;
  auto take = [&](size_t bytes) -> void* {
    void* p = (void*)w;
    w += (bytes + 255) & ~(size_t)255;
    return p;
  };
  int*   counts = (int*)take((size_t)N * 4);
  int*   rowptr = (int*)take((size_t)(N + 1) * 4);
  int*   cursor = (int*)take((size_t)N * 4);
  float* dinv   = (float*)take((size_t)N * 4);
  int*   col    = (int*)take((size_t)E * 4);
  float* bufA   = (float*)take((size_t)N * 128 * 4);
  float* bufB   = (float*)take((size_t)N * 128 * 4);

  // CSR build
  k_zero_i32<<<(N + 255) / 256, 256, 0, stream>>>(counts, N);
  k_count<<<(E + 255) / 256, 256, 0, stream>>>(edst, E, counts);
  k_scan<<<1, 1024, 0, stream>>>(counts, N, E, rowptr, cursor, dinv);
  k_fill<<<(E + 255) / 256, 256, 0, stream>>>(esrc, edst, E, cursor, col);

  const int aggblocks = (N + 3) / 4;
  const int gemmblocks = (N + 63) / 64;

  // layer 1: agg(x) @ W1^T + b1, relu
  k_agg64<0><<<aggblocks, 256, 0, stream>>>(x, dinv, rowptr, col, nullptr, bufA, N);
  k_gemm<64, 128, true, true><<<gemmblocks, 256, 0, stream>>>(bufA, W1, b1, bufB, N);

  // layer 2: agg(h1) @ W2^T + b2, relu
  k_agg128<<<aggblocks, 256, 0, stream>>>(bufB, dinv, rowptr, col, bufA, N);
  k_gemm<128, 128, true, true><<<gemmblocks, 256, 0, stream>>>(bufA, W2, b2, bufB, N);

  // layer 3: agg(h2 @ W3^T) + b3, softmax
  k_gemm<128, 64, false, false><<<gemmblocks, 256, 0, stream>>>(bufB, W3, nullptr, bufA, N);
  k_agg64<1><<<aggblocks, 256, 0, stream>>>(bufA, dinv, rowptr, col, b3, out, N);
}

// Round 2
// 759.685 us; speedup vs baseline: 1.3365x; 1.3365x over previous
//
#include <hip/hip_runtime.h>
#include <hip/hip_bf16.h>

// GCN 3-layer forward on MI355X.
// N=100000 nodes, E=1.6M edges, F=64, HID1=HID2=128.
//
// Key identities used:
//   out = A_norm @ (x @ W^T) + b  ==  (A_norm @ x) @ W^T + b   (agg is linear)
//   -> aggregate at 64 feats for layers 1 and 3, 128 for layer 2.
//   A_norm row i:  agg[i] = dinv[i] * ( sum_{e->i} dinv[src_e]*h[src_e] + dinv[i]*h[i] )
// CSR built on-device each call (counts -> 3-pass parallel scan -> fill);
// pull-based agg, no atomics on feature data.

#define TPB 256
#define SCAN_CHUNK 1024  // counts elements per scan block

// ---------------- CSR build ----------------

__global__ void k_zero_i32(int* __restrict__ p, int n) {
  int i = blockIdx.x * blockDim.x + threadIdx.x;
  if (i < n) p[i] = 0;
}

__global__ void k_count(const int* __restrict__ dst, int E, int* __restrict__ counts) {
  int e = blockIdx.x * blockDim.x + threadIdx.x;
  if (e < E) atomicAdd(&counts[dst[e]], 1);
}

// pass 1: per-block sums of counts
__global__ __launch_bounds__(256) void k_blocksum(const int* __restrict__ counts, int N,
                                                  int* __restrict__ bsum) {
  __shared__ int red[256];
  int b = blockIdx.x, t = threadIdx.x;
  int base = b * SCAN_CHUNK;
  int s = 0;
  for (int i = t; i < SCAN_CHUNK; i += 256) {
    int idx = base + i;
    if (idx < N) s += counts[idx];
  }
  red[t] = s;
  __syncthreads();
  for (int off = 128; off > 0; off >>= 1) {
    if (t < off) red[t] += red[t + off];
    __syncthreads();
  }
  if (t == 0) bsum[b] = red[0];
}

// pass 2: exclusive scan of block sums (NB <= 1024)
__global__ __launch_bounds__(1024) void k_scan_bsum(const int* __restrict__ bsum, int NB,
                                                    int* __restrict__ boff) {
  __shared__ int sh[1024];
  int t = threadIdx.x;
  int v = (t < NB) ? bsum[t] : 0;
  sh[t] = v;
  __syncthreads();
  for (int off = 1; off < 1024; off <<= 1) {
    int u = (t >= off) ? sh[t - off] : 0;
    __syncthreads();
    sh[t] += u;
    __syncthreads();
  }
  if (t < NB) boff[t] = sh[t] - v;
}

// pass 3: per-block scan of counts chunk; writes rowptr/cursor/dinv
__global__ __launch_bounds__(256) void k_blockscan(const int* __restrict__ counts, int N, int E,
                                                   const int* __restrict__ boff,
                                                   int* __restrict__ rowptr,
                                                   int* __restrict__ cursor,
                                                   float* __restrict__ dinv) {
  __shared__ int tsum[256];
  int b = blockIdx.x, t = threadIdx.x;
  int base = b * SCAN_CHUNK + t * 4;
  int c[4];
  int s = 0;
#pragma unroll
  for (int k = 0; k < 4; ++k) {
    int idx = base + k;
    c[k] = (idx < N) ? counts[idx] : 0;
    s += c[k];
  }
  tsum[t] = s;
  __syncthreads();
  for (int off = 1; off < 256; off <<= 1) {
    int v = (t >= off) ? tsum[t - off] : 0;
    __syncthreads();
    tsum[t] += v;
    __syncthreads();
  }
  int run = boff[b] + tsum[t] - s;  // exclusive prefix of this thread's first element
#pragma unroll
  for (int k = 0; k < 4; ++k) {
    int idx = base + k;
    if (idx < N) {
      rowptr[idx] = run;
      cursor[idx] = run;
      dinv[idx] = rsqrtf((float)(c[k] + 1));  // +1 = self-loop
      run += c[k];
    }
  }
  if (b == 0 && t == 0) rowptr[N] = E;
}

__global__ void k_fill(const int* __restrict__ src, const int* __restrict__ dst, int E,
                       int* __restrict__ cursor, int* __restrict__ col) {
  int e = blockIdx.x * blockDim.x + threadIdx.x;
  if (e < E) {
    int d = dst[e];
    int pos = atomicAdd(&cursor[d], 1);
    col[pos] = src[e];
  }
}

// ---------------- aggregation (pull, wave per row) ----------------

// F=64: lane = feature. EPI: 0 = plain, 1 = +bias then row-softmax.
template <int EPI>
__global__ void k_agg64(const float* __restrict__ h, const float* __restrict__ dinv,
                        const int* __restrict__ rowptr, const int* __restrict__ col,
                        const float* __restrict__ bias, float* __restrict__ out, int N) {
  int wid = blockIdx.x * (TPB / 64) + (threadIdx.x >> 6);
  int lane = threadIdx.x & 63;
  if (wid >= N) return;
  float di = dinv[wid];
  float acc = di * h[(size_t)wid * 64 + lane];  // self-loop term (inside di* scale)
  int r0 = rowptr[wid], r1 = rowptr[wid + 1];
  for (int base = r0; base < r1; base += 64) {
    int m = min(64, r1 - base);
    int ce = (base + lane < r1) ? col[base + lane] : 0;
    for (int j = 0; j < m; ++j) {
      int s2 = __shfl(ce, j);
      acc += dinv[s2] * h[(size_t)s2 * 64 + lane];
    }
  }
  float v = di * acc;
  if (EPI == 1) {
    v += bias[lane];
    float mx = v;
    #pragma unroll
    for (int o = 32; o > 0; o >>= 1) mx = fmaxf(mx, __shfl_xor(mx, o));
    float p = expf(v - mx);
    float sum = p;
    #pragma unroll
    for (int o = 32; o > 0; o >>= 1) sum += __shfl_xor(sum, o);
    v = p / sum;
  }
  out[(size_t)wid * 64 + lane] = v;
}

// F=128: lane handles 2 consecutive feats (float2).
__global__ void k_agg128(const float* __restrict__ h, const float* __restrict__ dinv,
                         const int* __restrict__ rowptr, const int* __restrict__ col,
                         float* __restrict__ out, int N) {
  int wid = blockIdx.x * (TPB / 64) + (threadIdx.x >> 6);
  int lane = threadIdx.x & 63;
  if (wid >= N) return;
  float di = dinv[wid];
  const float2* h2 = (const float2*)h;
  float2 hv = h2[(size_t)wid * 64 + lane];
  float ax = di * hv.x, ay = di * hv.y;
  int r0 = rowptr[wid], r1 = rowptr[wid + 1];
  for (int base = r0; base < r1; base += 64) {
    int m = min(64, r1 - base);
    int ce = (base + lane < r1) ? col[base + lane] : 0;
    for (int j = 0; j < m; ++j) {
      int s2 = __shfl(ce, j);
      float ds = dinv[s2];
      float2 hh = h2[(size_t)s2 * 64 + lane];
      ax += ds * hh.x;
      ay += ds * hh.y;
    }
  }
  float2 o;
  o.x = di * ax;
  o.y = di * ay;
  ((float2*)out)[(size_t)wid * 64 + lane] = o;
}

// ---------------- dense GEMM: out[M][NOUT] = in[M][K] @ W[NOUT][K]^T (+bias)(relu) ----------------

template <int K, int NOUT, bool RELU, bool BIAS>
__global__ __launch_bounds__(256) void k_gemm(const float* __restrict__ in,
                                              const float* __restrict__ W,
                                              const float* __restrict__ bias,
                                              float* __restrict__ out, int M) {
  constexpr int KC = 64;           // K-chunk staged in LDS
  constexpr int R = 64;            // rows per block
  constexpr int TN = 4;            // cols per thread
  constexpr int NG = NOUT / TN;    // col groups (32 or 16)
  constexpr int RG = 256 / NG;     // row groups (8 or 16)
  constexpr int TM = R / RG;       // rows per thread (8 or 4)

  __shared__ float wT[KC][NOUT + 4];   // W^T chunk, padded
  __shared__ float inT[KC][R + 4];     // input^T chunk, padded

  int t = threadIdx.x;
  int ng = t % NG, rg = t / NG;
  int n0 = ng * TN, r0 = rg * TM;
  int rowbase = blockIdx.x * R;

  float acc[TM][TN];
  #pragma unroll
  for (int i = 0; i < TM; ++i)
    #pragma unroll
    for (int j = 0; j < TN; ++j) acc[i][j] = 0.0f;

  for (int kc = 0; kc < K; kc += KC) {
    // stage W chunk transposed: wT[k][n] = W[n][kc+k]
    constexpr int WF4 = NOUT * KC / 4;
    for (int m = t; m < WF4; m += 256) {
      int kk4 = m % (KC / 4);
      int n = m / (KC / 4);
      const float4 w4 = *(const float4*)&W[(size_t)n * K + kc + kk4 * 4];
      wT[kk4 * 4 + 0][n] = w4.x;
      wT[kk4 * 4 + 1][n] = w4.y;
      wT[kk4 * 4 + 2][n] = w4.z;
      wT[kk4 * 4 + 3][n] = w4.w;
    }
    // stage input chunk transposed: inT[k][r] = in[rowbase+r][kc+k]
    constexpr int IF4 = R * KC / 4;
    for (int m = t; m < IF4; m += 256) {
      int kk4 = m % (KC / 4);
      int r = m / (KC / 4);
      int row = rowbase + r;
      float4 v4 = make_float4(0.f, 0.f, 0.f, 0.f);
      if (row < M) v4 = *(const float4*)&in[(size_t)row * K + kc + kk4 * 4];
      inT[kk4 * 4 + 0][r] = v4.x;
      inT[kk4 * 4 + 1][r] = v4.y;
      inT[kk4 * 4 + 2][r] = v4.z;
      inT[kk4 * 4 + 3][r] = v4.w;
    }
    __syncthreads();

    #pragma unroll 8
    for (int k = 0; k < KC; ++k) {
      float4 w4 = *(const float4*)&wT[k][n0];
      float iv[TM];
      #pragma unroll
      for (int i = 0; i < TM; ++i) iv[i] = inT[k][r0 + i];
      #pragma unroll
      for (int i = 0; i < TM; ++i) {
        acc[i][0] += iv[i] * w4.x;
        acc[i][1] += iv[i] * w4.y;
        acc[i][2] += iv[i] * w4.z;
        acc[i][3] += iv[i] * w4.w;
      }
    }
    __syncthreads();
  }

  float4 b4 = make_float4(0.f, 0.f, 0.f, 0.f);
  if (BIAS) b4 = *(const float4*)&bias[n0];
  #pragma unroll
  for (int i = 0; i < TM; ++i) {
    int row = rowbase + r0 + i;
    if (row < M) {
      float4 o;
      o.x = acc[i][0] + b4.x;
      o.y = acc[i][1] + b4.y;
      o.z = acc[i][2] + b4.z;
      o.w = acc[i][3] + b4.w;
      if (RELU) {
        o.x = fmaxf(o.x, 0.f);
        o.y = fmaxf(o.y, 0.f);
        o.z = fmaxf(o.z, 0.f);
        o.w = fmaxf(o.w, 0.f);
      }
      *(float4*)&out[(size_t)row * NOUT + n0] = o;
    }
  }
}

// ---------------- launch ----------------

extern "C" void kernel_launch(void* const* d_in, const int* in_sizes, int n_in,
                              void* d_out, int out_size, void* d_ws, size_t ws_size,
                              hipStream_t stream) {
  const float* x  = (const float*)d_in[0];
  const int*   ei = (const int*)d_in[1];
  const float* W1 = (const float*)d_in[2];
  const float* b1 = (const float*)d_in[3];
  const float* W2 = (const float*)d_in[4];
  const float* b2 = (const float*)d_in[5];
  const float* W3 = (const float*)d_in[6];
  const float* b3 = (const float*)d_in[7];
  float* out = (float*)d_out;

  const int N = in_sizes[0] / 64;
  const int E = in_sizes[1] / 2;
  const int* esrc = ei;
  const int* edst = ei + E;
  const int NB = (N + SCAN_CHUNK - 1) / SCAN_CHUNK;

  // workspace carve (256B-aligned regions)
  char* w = (char*)d_ws;
  auto take = [&](size_t bytes) -> void* {
    void* p = (void*)w;
    w += (bytes + 255) & ~(size_t)255;
    return p;
  };
  int*   counts = (int*)take((size_t)N * 4);
  int*   rowptr = (int*)take((size_t)(N + 1) * 4);
  int*   cursor = (int*)take((size_t)N * 4);
  float* dinv   = (float*)take((size_t)N * 4);
  int*   col    = (int*)take((size_t)E * 4);
  int*   bsum   = (int*)take((size_t)NB * 4);
  int*   boff   = (int*)take((size_t)NB * 4);
  float* bufA   = (float*)take((size_t)N * 128 * 4);
  float* bufB   = (float*)take((size_t)N * 128 * 4);

  // CSR build
  k_zero_i32<<<(N + 255) / 256, 256, 0, stream>>>(counts, N);
  k_count<<<(E + 255) / 256, 256, 0, stream>>>(edst, E, counts);
  k_blocksum<<<NB, 256, 0, stream>>>(counts, N, bsum);
  k_scan_bsum<<<1, 1024, 0, stream>>>(bsum, NB, boff);
  k_blockscan<<<NB, 256, 0, stream>>>(counts, N, E, boff, rowptr, cursor, dinv);
  k_fill<<<(E + 255) / 256, 256, 0, stream>>>(esrc, edst, E, cursor, col);

  const int aggblocks = (N + 3) / 4;
  const int gemmblocks = (N + 63) / 64;

  // layer 1: agg(x) @ W1^T + b1, relu
  k_agg64<0><<<aggblocks, 256, 0, stream>>>(x, dinv, rowptr, col, nullptr, bufA, N);
  k_gemm<64, 128, true, true><<<gemmblocks, 256, 0, stream>>>(bufA, W1, b1, bufB, N);

  // layer 2: agg(h1) @ W2^T + b2, relu
  k_agg128<<<aggblocks, 256, 0, stream>>>(bufB, dinv, rowptr, col, bufA, N);
  k_gemm<128, 128, true, true><<<gemmblocks, 256, 0, stream>>>(bufA, W2, b2, bufB, N);

  // layer 3: agg(h2 @ W3^T) + b3, softmax
  k_gemm<128, 64, false, false><<<gemmblocks, 256, 0, stream>>>(bufB, W3, nullptr, bufA, N);
  k_agg64<1><<<aggblocks, 256, 0, stream>>>(bufA, dinv, rowptr, col, b3, out, N);
}